// Round 1
// baseline (541.694 us; speedup 1.0000x reference)
//
#include <hip/hip_runtime.h>
#include <math.h>

#define BLOCK 256

__global__ __launch_bounds__(BLOCK) void margin_loss_kernel(
    const float* __restrict__ cos_theta,
    const int*   __restrict__ labels,
    const float* __restrict__ margins,
    float*       __restrict__ out,
    int B, int C)
{
    constexpr float SCALE = 64.0f;
    constexpr float EPS   = 1e-7f;
    const int row = blockIdx.x;
    const float* rowbase = cos_theta + (size_t)row * (size_t)C;
    const float4* rowp = (const float4*)rowbase;
    const int n4 = C >> 2;

    // Single pass: sum exp(SCALE*x - SCALE). Logits bounded by SCALE, so the
    // fixed shift SCALE is a valid (and tight) max surrogate; underflowed
    // terms are negligible (< C * 1.4e-45).
    float s = 0.0f;
    for (int t = threadIdx.x; t < n4; t += BLOCK) {
        float4 v = rowp[t];
        float x0 = fminf(fmaxf(v.x, -1.0f + EPS), 1.0f - EPS);
        float x1 = fminf(fmaxf(v.y, -1.0f + EPS), 1.0f - EPS);
        float x2 = fminf(fmaxf(v.z, -1.0f + EPS), 1.0f - EPS);
        float x3 = fminf(fmaxf(v.w, -1.0f + EPS), 1.0f - EPS);
        s += __expf(fmaf(SCALE, x0, -SCALE));
        s += __expf(fmaf(SCALE, x1, -SCALE));
        s += __expf(fmaf(SCALE, x2, -SCALE));
        s += __expf(fmaf(SCALE, x3, -SCALE));
    }
    // tail (C % 4) — none for C=50000, kept for safety
    for (int c = (n4 << 2) + threadIdx.x; c < C; c += BLOCK) {
        float x = fminf(fmaxf(rowbase[c], -1.0f + EPS), 1.0f - EPS);
        s += __expf(fmaf(SCALE, x, -SCALE));
    }

    // wave (64-lane) shuffle reduction
    for (int off = 32; off > 0; off >>= 1)
        s += __shfl_down(s, off);

    __shared__ float ws[BLOCK / 64];
    const int lane = threadIdx.x & 63;
    const int wid  = threadIdx.x >> 6;
    if (lane == 0) ws[wid] = s;
    __syncthreads();

    if (threadIdx.x == 0) {
        float tot = 0.0f;
        #pragma unroll
        for (int w = 0; w < BLOCK / 64; ++w) tot += ws[w];

        // Fixup: replace the label column's term with the margin-adjusted one.
        const int lbl = labels[row];
        const float m = margins[lbl];
        float ct = rowbase[lbl];
        ct = fminf(fmaxf(ct, -1.0f + EPS), 1.0f - EPS);
        const float cm = cosf(m);
        const float sm = sinf(m);
        const float sin_t = sqrtf(fmaxf(1.0f - ct * ct, 0.0f));
        const float target = ct * cm - sin_t * sm;   // cos(theta + m)

        tot += __expf(fmaf(SCALE, target, -SCALE)) - __expf(fmaf(SCALE, ct, -SCALE));

        const float lse = SCALE + logf(tot);          // logsumexp of the row
        const float contrib = (lse - SCALE * target) / (float)B;
        atomicAdd(out, contrib);                      // device-scope by default
    }
}

extern "C" void kernel_launch(void* const* d_in, const int* in_sizes, int n_in,
                              void* d_out, int out_size, void* d_ws, size_t ws_size,
                              hipStream_t stream) {
    const float* cos_theta = (const float*)d_in[0];
    const int*   labels    = (const int*)d_in[1];
    const float* margins   = (const float*)d_in[2];
    float* out = (float*)d_out;

    const int B = in_sizes[1];   // 2048
    const int C = in_sizes[2];   // 50000

    // d_out is re-poisoned to 0xAA before every timed launch — zero it first.
    hipMemsetAsync(out, 0, sizeof(float) * (size_t)out_size, stream);

    margin_loss_kernel<<<dim3(B), dim3(BLOCK), 0, stream>>>(
        cos_theta, labels, margins, out, B, C);
}

// Round 2
// 540.967 us; speedup vs baseline: 1.0013x; 1.0013x over previous
//
#include <hip/hip_runtime.h>
#include <math.h>

#define BLOCK 256

__global__ __launch_bounds__(BLOCK) void margin_loss_kernel(
    const float* __restrict__ cos_theta,
    const int*   __restrict__ labels,
    const float* __restrict__ margins,
    float*       __restrict__ out,
    int B, int C)
{
    constexpr float SCALE = 64.0f;
    constexpr float EPS   = 1e-7f;
    const int row = blockIdx.x;
    const float* rowbase = cos_theta + (size_t)row * (size_t)C;

    // --- Early broadcast loads for the label-column fixup (overlap their
    // ~900-cycle HBM latency with the streaming loop instead of serializing
    // after the reduction). Same address across all lanes -> 1 transaction.
    const int   lbl    = labels[row];
    const float m      = margins[lbl];
    const float ct_raw = rowbase[lbl];

    const float4* rowp = (const float4*)rowbase;
    const int n4 = C >> 2;

    // Single pass: sum exp(SCALE*x - SCALE). Logits bounded by SCALE, so the
    // fixed shift SCALE is a valid max surrogate; underflowed terms < C*1.4e-45.
    // 2-way unroll, two accumulators, two loads in flight per iteration.
    float s0 = 0.0f, s1 = 0.0f;
    int t = threadIdx.x;
    for (; t + BLOCK < n4; t += 2 * BLOCK) {
        float4 a = rowp[t];
        float4 b = rowp[t + BLOCK];
        float a0 = fminf(fmaxf(a.x, -1.0f + EPS), 1.0f - EPS);
        float a1 = fminf(fmaxf(a.y, -1.0f + EPS), 1.0f - EPS);
        float a2 = fminf(fmaxf(a.z, -1.0f + EPS), 1.0f - EPS);
        float a3 = fminf(fmaxf(a.w, -1.0f + EPS), 1.0f - EPS);
        float b0 = fminf(fmaxf(b.x, -1.0f + EPS), 1.0f - EPS);
        float b1 = fminf(fmaxf(b.y, -1.0f + EPS), 1.0f - EPS);
        float b2 = fminf(fmaxf(b.z, -1.0f + EPS), 1.0f - EPS);
        float b3 = fminf(fmaxf(b.w, -1.0f + EPS), 1.0f - EPS);
        s0 += __expf(fmaf(SCALE, a0, -SCALE));
        s1 += __expf(fmaf(SCALE, b0, -SCALE));
        s0 += __expf(fmaf(SCALE, a1, -SCALE));
        s1 += __expf(fmaf(SCALE, b1, -SCALE));
        s0 += __expf(fmaf(SCALE, a2, -SCALE));
        s1 += __expf(fmaf(SCALE, b2, -SCALE));
        s0 += __expf(fmaf(SCALE, a3, -SCALE));
        s1 += __expf(fmaf(SCALE, b3, -SCALE));
    }
    if (t < n4) {
        float4 a = rowp[t];
        float a0 = fminf(fmaxf(a.x, -1.0f + EPS), 1.0f - EPS);
        float a1 = fminf(fmaxf(a.y, -1.0f + EPS), 1.0f - EPS);
        float a2 = fminf(fmaxf(a.z, -1.0f + EPS), 1.0f - EPS);
        float a3 = fminf(fmaxf(a.w, -1.0f + EPS), 1.0f - EPS);
        s0 += __expf(fmaf(SCALE, a0, -SCALE));
        s0 += __expf(fmaf(SCALE, a1, -SCALE));
        s0 += __expf(fmaf(SCALE, a2, -SCALE));
        s0 += __expf(fmaf(SCALE, a3, -SCALE));
    }
    // scalar tail (C % 4) — none for C=50000, kept for safety
    for (int c = (n4 << 2) + threadIdx.x; c < C; c += BLOCK) {
        float x = fminf(fmaxf(rowbase[c], -1.0f + EPS), 1.0f - EPS);
        s0 += __expf(fmaf(SCALE, x, -SCALE));
    }
    float s = s0 + s1;

    // wave (64-lane) shuffle reduction
    for (int off = 32; off > 0; off >>= 1)
        s += __shfl_down(s, off);

    __shared__ float ws[BLOCK / 64];
    const int lane = threadIdx.x & 63;
    const int wid  = threadIdx.x >> 6;
    if (lane == 0) ws[wid] = s;
    __syncthreads();

    if (threadIdx.x == 0) {
        float tot = 0.0f;
        #pragma unroll
        for (int w = 0; w < BLOCK / 64; ++w) tot += ws[w];

        // Fixup: replace the label column's term with the margin-adjusted one.
        const float ct = fminf(fmaxf(ct_raw, -1.0f + EPS), 1.0f - EPS);
        const float cm = cosf(m);
        const float sm = sinf(m);
        const float sin_t = sqrtf(fmaxf(1.0f - ct * ct, 0.0f));
        const float target = ct * cm - sin_t * sm;   // cos(theta + m)

        tot += __expf(fmaf(SCALE, target, -SCALE)) - __expf(fmaf(SCALE, ct, -SCALE));

        const float lse = SCALE + logf(tot);          // logsumexp of the row
        const float contrib = (lse - SCALE * target) / (float)B;
        atomicAdd(out, contrib);                      // device-scope by default
    }
}

extern "C" void kernel_launch(void* const* d_in, const int* in_sizes, int n_in,
                              void* d_out, int out_size, void* d_ws, size_t ws_size,
                              hipStream_t stream) {
    const float* cos_theta = (const float*)d_in[0];
    const int*   labels    = (const int*)d_in[1];
    const float* margins   = (const float*)d_in[2];
    float* out = (float*)d_out;

    const int B = in_sizes[1];   // 2048
    const int C = in_sizes[2];   // 50000

    // d_out is re-poisoned to 0xAA before every timed launch — zero it first.
    hipMemsetAsync(out, 0, sizeof(float) * (size_t)out_size, stream);

    margin_loss_kernel<<<dim3(B), dim3(BLOCK), 0, stream>>>(
        cos_theta, labels, margins, out, B, C);
}